// Round 1
// baseline (158.772 us; speedup 1.0000x reference)
//
#include <hip/hip_runtime.h>
#include <hip/hip_bf16.h>

#define C 256
#define C2 128
#define NTOK 10368
#define NS 18
#define CHUNK (NTOK / NS)   // 576

typedef __bf16 bf16x8 __attribute__((ext_vector_type(8)));
typedef float  f32x4  __attribute__((ext_vector_type(4)));

static __device__ inline bf16x8 pack8(const float4 a, const float4 b) {
    bf16x8 r;
    r[0] = (__bf16)a.x; r[1] = (__bf16)a.y; r[2] = (__bf16)a.z; r[3] = (__bf16)a.w;
    r[4] = (__bf16)b.x; r[5] = (__bf16)b.y; r[6] = (__bf16)b.z; r[7] = (__bf16)b.w;
    return r;
}

// ---------------- kernel 1: s[r] = sum_n feat[r, n] ----------------
__global__ __launch_bounds__(256) void k_rowsum(const float* __restrict__ feat,
                                                float* __restrict__ s) {
    int r = blockIdx.x;
    int t = threadIdx.x;
    float acc = 0.f;
    for (int n = t; n < NTOK; n += 256) acc += feat[r * NTOK + n];
    // wave64 reduce
    for (int off = 32; off > 0; off >>= 1) acc += __shfl_xor(acc, off);
    __shared__ float red[4];
    int wave = t >> 6, lane = t & 63;
    if (lane == 0) red[wave] = acc;
    __syncthreads();
    if (t == 0) s[r] = red[0] + red[1] + red[2] + red[3];
}

// ---------------- kernel 2: Gpart[nc] += feat[:, chunk] @ feat[:, chunk]^T ----------------
// block = 256 thr (4 waves); block tile 64x64 of G; grid (4,4,NS)
__global__ __launch_bounds__(256) void k_gram_partial(const float* __restrict__ feat,
                                                      float* __restrict__ Gpart) {
    int it = blockIdx.x, jt = blockIdx.y, nc = blockIdx.z;
    int tid = threadIdx.x;
    int wave = tid >> 6;
    int lane = tid & 63;
    int l15 = lane & 15;
    int lq  = lane >> 4;

    int i_row = it * 64 + wave * 16 + l15;          // A fragment row
    const float* fA = feat + (size_t)i_row * NTOK;

    f32x4 acc[4];
    for (int f = 0; f < 4; ++f) acc[f] = (f32x4){0.f, 0.f, 0.f, 0.f};

    for (int ks = 0; ks < CHUNK / 32; ++ks) {
        int n0 = nc * CHUNK + ks * 32 + lq * 8;
        const float4* ap = (const float4*)(fA + n0);
        bf16x8 afrag = pack8(ap[0], ap[1]);
#pragma unroll
        for (int f = 0; f < 4; ++f) {
            int j_row = jt * 64 + f * 16 + l15;     // B fragment row
            const float4* bp = (const float4*)(feat + (size_t)j_row * NTOK + n0);
            bf16x8 bfrag = pack8(bp[0], bp[1]);
            acc[f] = __builtin_amdgcn_mfma_f32_16x16x32_bf16(afrag, bfrag, acc[f], 0, 0, 0);
        }
    }

    float* Gp = Gpart + (size_t)nc * (C * C);
#pragma unroll
    for (int f = 0; f < 4; ++f)
#pragma unroll
        for (int r = 0; r < 4; ++r) {
            int gi = it * 64 + wave * 16 + lq * 4 + r;   // row
            int gj = jt * 64 + f * 16 + l15;             // col
            Gp[gi * C + gj] = acc[f][r];
        }
}

// ---------------- kernel 3: G = sum_p Gpart[p] ----------------
__global__ __launch_bounds__(256) void k_gram_reduce(const float* __restrict__ Gpart,
                                                     float* __restrict__ G) {
    int idx = blockIdx.x * 256 + threadIdx.x;
    float a = 0.f;
    for (int p = 0; p < NS; ++p) a += Gpart[(size_t)p * (C * C) + idx];
    G[idx] = a;
}

// ---------------- kernel 4: M[m,c] = sum_k Wj[m,k] G[k,c] + bj[m] s[c] ----------------
__global__ __launch_bounds__(256) void k_M(const float* __restrict__ Wj,
                                           const float* __restrict__ bj,
                                           const float* __restrict__ G,
                                           const float* __restrict__ s,
                                           float* __restrict__ M) {
    int m = blockIdx.x;      // 0..127
    int c = threadIdx.x;     // 0..255
    float acc = bj[m] * s[c];
    for (int k = 0; k < C; ++k) acc += Wj[m * C + k] * G[k * C + c];
    M[m * C + c] = acc;
}

// ---------------- kernel 5: Pt[c,k] = (sum_m Wi[m,k] M[m,c])/N  (bf16),  q[c] = (sum_m bi[m] M[m,c])/N
__global__ __launch_bounds__(256) void k_P(const float* __restrict__ Wi,
                                           const float* __restrict__ bi,
                                           const float* __restrict__ M,
                                           __bf16* __restrict__ Pt,
                                           float* __restrict__ q) {
    int c = blockIdx.x;      // 0..255
    int k = threadIdx.x;     // 0..255
    float acc = 0.f;
    for (int m = 0; m < C2; ++m) acc += Wi[m * C + k] * M[m * C + c];
    Pt[c * C + k] = (__bf16)(acc * (1.0f / NTOK));

    float qv = (k < C2) ? bi[k] * M[k * C + c] : 0.f;
    for (int off = 32; off > 0; off >>= 1) qv += __shfl_xor(qv, off);
    __shared__ float red[4];
    int wave = k >> 6, lane = k & 63;
    if (lane == 0) red[wave] = qv;
    __syncthreads();
    if (k == 0) q[c] = (red[0] + red[1] + red[2] + red[3]) * (1.0f / NTOK);
}

// ---------------- kernel 6: out[c,n] = feat[c,n] + q[c] + sum_k Pt[c,k] feat[k,n] ----------------
// grid = 324 n-tiles of 32; block = 256 thr (4 waves); each wave: 4 c-strips of 16 x 2 n-subtiles
__global__ __launch_bounds__(256) void k_final(const float* __restrict__ feat,
                                               const __bf16* __restrict__ Pt,
                                               const float* __restrict__ q,
                                               float* __restrict__ out) {
    __shared__ __align__(16) __bf16 Bs[32][40];   // [n-local][k-local], pitch 40 (80B, 16B-aligned)

    int n0 = blockIdx.x * 32;
    int tid = threadIdx.x;
    int wave = tid >> 6;
    int lane = tid & 63;
    int l15 = lane & 15;
    int lq  = lane >> 4;

    int kk = tid >> 3;         // 0..31  (k-local row to stage)
    int nn = (tid & 7) * 4;    // 0..28  (n-local col group)

    f32x4 acc[4][2];
#pragma unroll
    for (int si = 0; si < 4; ++si)
#pragma unroll
        for (int ns = 0; ns < 2; ++ns) acc[si][ns] = (f32x4){0.f, 0.f, 0.f, 0.f};

    for (int ks = 0; ks < 8; ++ks) {
        int k0 = ks * 32;
        float4 v = *(const float4*)(feat + (size_t)(k0 + kk) * NTOK + n0 + nn);
        __syncthreads();                       // previous iter's reads done
        Bs[nn + 0][kk] = (__bf16)v.x;
        Bs[nn + 1][kk] = (__bf16)v.y;
        Bs[nn + 2][kk] = (__bf16)v.z;
        Bs[nn + 3][kk] = (__bf16)v.w;
        __syncthreads();

        bf16x8 b[2];
#pragma unroll
        for (int ns = 0; ns < 2; ++ns)
            b[ns] = *(const bf16x8*)&Bs[ns * 16 + l15][lq * 8];

#pragma unroll
        for (int si = 0; si < 4; ++si) {
            int crow = wave * 64 + si * 16 + l15;
            bf16x8 a = *(const bf16x8*)(Pt + (size_t)crow * C + k0 + lq * 8);
#pragma unroll
            for (int ns = 0; ns < 2; ++ns)
                acc[si][ns] = __builtin_amdgcn_mfma_f32_16x16x32_bf16(a, b[ns], acc[si][ns], 0, 0, 0);
        }
    }

#pragma unroll
    for (int si = 0; si < 4; ++si)
#pragma unroll
        for (int ns = 0; ns < 2; ++ns)
#pragma unroll
            for (int r = 0; r < 4; ++r) {
                int c = wave * 64 + si * 16 + lq * 4 + r;
                int n = n0 + ns * 16 + l15;
                out[(size_t)c * NTOK + n] = feat[(size_t)c * NTOK + n] + q[c] + acc[si][ns][r];
            }
}

extern "C" void kernel_launch(void* const* d_in, const int* in_sizes, int n_in,
                              void* d_out, int out_size, void* d_ws, size_t ws_size,
                              hipStream_t stream) {
    const float* feat = (const float*)d_in[0];   // [256, 10368]
    const float* Wi   = (const float*)d_in[1];   // [128, 256]
    const float* bi   = (const float*)d_in[2];   // [128]
    const float* Wj   = (const float*)d_in[3];   // [128, 256]
    const float* bj   = (const float*)d_in[4];   // [128]
    float* out = (float*)d_out;                  // [256, 10368]

    float* ws = (float*)d_ws;
    float*  s     = ws;                    // 256
    float*  q     = ws + 256;              // 256
    float*  G     = ws + 512;              // 65536
    float*  M     = ws + 66048;            // 32768
    __bf16* Pt    = (__bf16*)(ws + 98816); // 65536 bf16  (32768 floats of space)
    float*  Gpart = ws + 131584;           // NS * 65536 = 1,179,648 floats

    k_rowsum      <<<256, 256, 0, stream>>>(feat, s);
    k_gram_partial<<<dim3(4, 4, NS), 256, 0, stream>>>(feat, Gpart);
    k_gram_reduce <<<256, 256, 0, stream>>>(Gpart, G);
    k_M           <<<128, 256, 0, stream>>>(Wj, bj, G, s, M);
    k_P           <<<256, 256, 0, stream>>>(Wi, bi, M, Pt, q);
    k_final       <<<324, 256, 0, stream>>>(feat, Pt, q, out);
}

// Round 2
// 147.258 us; speedup vs baseline: 1.0782x; 1.0782x over previous
//
#include <hip/hip_runtime.h>
#include <hip/hip_bf16.h>

#define C 256
#define C2 128
#define NTOK 10368

typedef __bf16 bf16x8 __attribute__((ext_vector_type(8)));
typedef float  f32x4  __attribute__((ext_vector_type(4)));

// ws layout (float offsets)
#define WS_S      0          // 256
#define WS_Q      256        // 256
#define WS_G      512        // 65536
#define WS_M      66048      // 32768
#define WS_PT     98816      // 32768 float-slots = 65536 bf16
#define WS_SPART  131584     // 324*256 = 82944
#define WS_FEATT  214528     // 2,654,208 bf16 = 1,327,104 float-slots
#define WS_NEED_BYTES ((size_t)(214528 + 1327104) * 4)

#define GP_CHUNKS 40         // Gram partials, stored in d_out (40*65536 floats <= out_size)

static __device__ inline bf16x8 pack8(const float4 a, const float4 b) {
    bf16x8 r;
    r[0] = (__bf16)a.x; r[1] = (__bf16)a.y; r[2] = (__bf16)a.z; r[3] = (__bf16)a.w;
    r[4] = (__bf16)b.x; r[5] = (__bf16)b.y; r[6] = (__bf16)b.z; r[7] = (__bf16)b.w;
    return r;
}

// ---------- k_gram: Gpart[nc] = feat[:,chunk]@feat[:,chunk]^T, grid (4,4,40), tile 64x64 ----------
__global__ __launch_bounds__(256) void k_gram(const float* __restrict__ feat,
                                              float* __restrict__ Gpart) {
    int it = blockIdx.x, jt = blockIdx.y, nc = blockIdx.z;
    int tid = threadIdx.x;
    int wave = tid >> 6, lane = tid & 63;
    int l15 = lane & 15, lq = lane >> 4;

    int nsteps = (nc == GP_CHUNKS - 1) ? 12 : 8;   // 39*256 + 384 = 10368
    int nbase = nc * 256;

    int i_row = it * 64 + wave * 16 + l15;
    const float* fA = feat + (size_t)i_row * NTOK;

    f32x4 acc[4];
#pragma unroll
    for (int f = 0; f < 4; ++f) acc[f] = (f32x4){0.f, 0.f, 0.f, 0.f};

    for (int ks = 0; ks < nsteps; ++ks) {
        int n0 = nbase + ks * 32 + lq * 8;
        const float4* ap = (const float4*)(fA + n0);
        bf16x8 afrag = pack8(ap[0], ap[1]);
#pragma unroll
        for (int f = 0; f < 4; ++f) {
            int j_row = jt * 64 + f * 16 + l15;
            const float4* bp = (const float4*)(feat + (size_t)j_row * NTOK + n0);
            bf16x8 bfrag = pack8(bp[0], bp[1]);
            acc[f] = __builtin_amdgcn_mfma_f32_16x16x32_bf16(afrag, bfrag, acc[f], 0, 0, 0);
        }
    }

    float* Gp = Gpart + (size_t)nc * (C * C);
#pragma unroll
    for (int f = 0; f < 4; ++f)
#pragma unroll
        for (int r = 0; r < 4; ++r) {
            int gi = it * 64 + wave * 16 + lq * 4 + r;
            int gj = jt * 64 + f * 16 + l15;
            Gp[gi * C + gj] = acc[f][r];
        }
}

// ---------- k_trans: featT[n][c] = bf16(feat[c][n]); sPart[nc][c] = partial row sums ----------
// grid 324, n-tile 32, 256 threads (thread t = row c)
__global__ __launch_bounds__(256) void k_trans(const float* __restrict__ feat,
                                               __bf16* __restrict__ featT,
                                               float* __restrict__ sPart) {
    __shared__ __align__(16) ushort Ls[32][C];
    int n0 = blockIdx.x * 32;
    int c = threadIdx.x;

    float vals[32];
    float ssum = 0.f;
#pragma unroll
    for (int i = 0; i < 8; ++i) {
        float4 v = *(const float4*)(feat + (size_t)c * NTOK + n0 + i * 4);
        vals[i * 4 + 0] = v.x; vals[i * 4 + 1] = v.y;
        vals[i * 4 + 2] = v.z; vals[i * 4 + 3] = v.w;
        ssum += v.x + v.y + v.z + v.w;
    }
    sPart[blockIdx.x * C + c] = ssum;
#pragma unroll
    for (int n = 0; n < 32; ++n) {
        __bf16 b = (__bf16)vals[n];
        Ls[n][c] = *(ushort*)&b;
    }
    __syncthreads();
    int n = threadIdx.x >> 3;
    int koff = (threadIdx.x & 7) * 32;
    const uint4* src = (const uint4*)&Ls[n][koff];
    uint4* dst = (uint4*)(featT + (size_t)(n0 + n) * C + koff);
#pragma unroll
    for (int i = 0; i < 4; ++i) dst[i] = src[i];
}

// ---------- k_reduce: G = sum_p Gpart[p]; block 64 reduces sPart -> s ----------
__global__ __launch_bounds__(256) void k_reduce(const float* __restrict__ Gpart,
                                                const float* __restrict__ sPart,
                                                float* __restrict__ G,
                                                float* __restrict__ s,
                                                int have_spart) {
    if (blockIdx.x < 64) {
        int idx = (blockIdx.x * 256 + threadIdx.x) * 4;
        f32x4 a = (f32x4){0.f, 0.f, 0.f, 0.f};
        for (int p = 0; p < GP_CHUNKS; ++p) {
            const f32x4 v = *(const f32x4*)(Gpart + (size_t)p * (C * C) + idx);
            a += v;
        }
        *(f32x4*)(G + idx) = a;
    } else if (have_spart) {
        int c = threadIdx.x;
        float a = 0.f;
        for (int p = 0; p < 324; ++p) a += sPart[p * C + c];
        s[c] = a;
    }
}

// ---------- k_rowsum (fallback path): s[r] = sum_n feat[r,n] ----------
__global__ __launch_bounds__(256) void k_rowsum(const float* __restrict__ feat,
                                                float* __restrict__ s) {
    int r = blockIdx.x;
    int t = threadIdx.x;
    float acc = 0.f;
    for (int n4 = t * 4; n4 < NTOK; n4 += 1024) {
        float4 v = *(const float4*)(feat + (size_t)r * NTOK + n4);
        acc += v.x + v.y + v.z + v.w;
    }
    for (int off = 32; off > 0; off >>= 1) acc += __shfl_xor(acc, off);
    __shared__ float red[4];
    int wave = t >> 6, lane = t & 63;
    if (lane == 0) red[wave] = acc;
    __syncthreads();
    if (t == 0) s[r] = red[0] + red[1] + red[2] + red[3];
}

// ---------- k_M: M[m,c] = sum_k Wj[m,k] G[k,c] + bj[m] s[c] ----------
__global__ __launch_bounds__(256) void k_M(const float* __restrict__ Wj,
                                           const float* __restrict__ bj,
                                           const float* __restrict__ G,
                                           const float* __restrict__ s,
                                           float* __restrict__ M) {
    int m = blockIdx.x;
    int c = threadIdx.x;
    float acc = bj[m] * s[c];
#pragma unroll 4
    for (int k0 = 0; k0 < C; k0 += 4) {
        float4 w = *(const float4*)(Wj + m * C + k0);
        acc += w.x * G[(k0 + 0) * C + c];
        acc += w.y * G[(k0 + 1) * C + c];
        acc += w.z * G[(k0 + 2) * C + c];
        acc += w.w * G[(k0 + 3) * C + c];
    }
    M[m * C + c] = acc;
}

// ---------- k_P: Pt[c,k] = (sum_m Wi[m,k] M[m,c])/N (bf16); q[c] = (sum_m bi[m] M[m,c])/N ----------
__global__ __launch_bounds__(256) void k_P(const float* __restrict__ Wi,
                                           const float* __restrict__ bi,
                                           const float* __restrict__ M,
                                           __bf16* __restrict__ Pt,
                                           float* __restrict__ q) {
    int c = blockIdx.x;
    int k = threadIdx.x;
    float acc = 0.f;
#pragma unroll 8
    for (int m = 0; m < C2; ++m) acc += Wi[m * C + k] * M[m * C + c];
    Pt[c * C + k] = (__bf16)(acc * (1.0f / NTOK));

    float qv = (k < C2) ? bi[k] * M[k * C + c] : 0.f;
    for (int off = 32; off > 0; off >>= 1) qv += __shfl_xor(qv, off);
    __shared__ float red[4];
    int wave = k >> 6, lane = k & 63;
    if (lane == 0) red[wave] = qv;
    __syncthreads();
    if (k == 0) q[c] = (red[0] + red[1] + red[2] + red[3]) * (1.0f / NTOK);
}

// ---------- k_final (featT path): out[c,n] = feat[c,n] + q[c] + sum_k Pt[c,k] featT[n,k] ----------
// grid (324, 2): n-tile 32, c-half 128; 4 waves; no LDS, no barriers
__global__ __launch_bounds__(256) void k_final(const float* __restrict__ feat,
                                               const __bf16* __restrict__ featT,
                                               const __bf16* __restrict__ Pt,
                                               const float* __restrict__ q,
                                               float* __restrict__ out) {
    int n0 = blockIdx.x * 32;
    int cbase = blockIdx.y * 128;
    int tid = threadIdx.x;
    int wave = tid >> 6, lane = tid & 63;
    int l15 = lane & 15, lq = lane >> 4;

    f32x4 acc[2][2];
#pragma unroll
    for (int si = 0; si < 2; ++si)
#pragma unroll
        for (int ns = 0; ns < 2; ++ns) acc[si][ns] = (f32x4){0.f, 0.f, 0.f, 0.f};

#pragma unroll
    for (int ks = 0; ks < 8; ++ks) {
        int k0 = ks * 32;
        bf16x8 b[2];
#pragma unroll
        for (int ns = 0; ns < 2; ++ns)
            b[ns] = *(const bf16x8*)(featT + (size_t)(n0 + ns * 16 + l15) * C + k0 + lq * 8);
#pragma unroll
        for (int si = 0; si < 2; ++si) {
            int crow = cbase + wave * 32 + si * 16 + l15;
            bf16x8 a = *(const bf16x8*)(Pt + (size_t)crow * C + k0 + lq * 8);
#pragma unroll
            for (int ns = 0; ns < 2; ++ns)
                acc[si][ns] = __builtin_amdgcn_mfma_f32_16x16x32_bf16(a, b[ns], acc[si][ns], 0, 0, 0);
        }
    }

#pragma unroll
    for (int si = 0; si < 2; ++si)
#pragma unroll
        for (int ns = 0; ns < 2; ++ns)
#pragma unroll
            for (int r = 0; r < 4; ++r) {
                int c = cbase + wave * 32 + si * 16 + lq * 4 + r;
                int n = n0 + ns * 16 + l15;
                out[(size_t)c * NTOK + n] = feat[(size_t)c * NTOK + n] + q[c] + acc[si][ns][r];
            }
}

// ---------- k_final_lds (fallback, round-1 version) ----------
__global__ __launch_bounds__(256) void k_final_lds(const float* __restrict__ feat,
                                                   const __bf16* __restrict__ Pt,
                                                   const float* __restrict__ q,
                                                   float* __restrict__ out) {
    __shared__ __align__(16) __bf16 Bs[32][40];
    int n0 = blockIdx.x * 32;
    int tid = threadIdx.x;
    int wave = tid >> 6, lane = tid & 63;
    int l15 = lane & 15, lq = lane >> 4;
    int kk = tid >> 3;
    int nn = (tid & 7) * 4;

    f32x4 acc[4][2];
#pragma unroll
    for (int si = 0; si < 4; ++si)
#pragma unroll
        for (int ns = 0; ns < 2; ++ns) acc[si][ns] = (f32x4){0.f, 0.f, 0.f, 0.f};

    for (int ks = 0; ks < 8; ++ks) {
        int k0 = ks * 32;
        float4 v = *(const float4*)(feat + (size_t)(k0 + kk) * NTOK + n0 + nn);
        __syncthreads();
        Bs[nn + 0][kk] = (__bf16)v.x;
        Bs[nn + 1][kk] = (__bf16)v.y;
        Bs[nn + 2][kk] = (__bf16)v.z;
        Bs[nn + 3][kk] = (__bf16)v.w;
        __syncthreads();

        bf16x8 b[2];
#pragma unroll
        for (int ns = 0; ns < 2; ++ns)
            b[ns] = *(const bf16x8*)&Bs[ns * 16 + l15][lq * 8];
#pragma unroll
        for (int si = 0; si < 4; ++si) {
            int crow = wave * 64 + si * 16 + l15;
            bf16x8 a = *(const bf16x8*)(Pt + (size_t)crow * C + k0 + lq * 8);
#pragma unroll
            for (int ns = 0; ns < 2; ++ns)
                acc[si][ns] = __builtin_amdgcn_mfma_f32_16x16x32_bf16(a, b[ns], acc[si][ns], 0, 0, 0);
        }
    }
#pragma unroll
    for (int si = 0; si < 4; ++si)
#pragma unroll
        for (int ns = 0; ns < 2; ++ns)
#pragma unroll
            for (int r = 0; r < 4; ++r) {
                int c = wave * 64 + si * 16 + lq * 4 + r;
                int n = n0 + ns * 16 + l15;
                out[(size_t)c * NTOK + n] = feat[(size_t)c * NTOK + n] + q[c] + acc[si][ns][r];
            }
}

extern "C" void kernel_launch(void* const* d_in, const int* in_sizes, int n_in,
                              void* d_out, int out_size, void* d_ws, size_t ws_size,
                              hipStream_t stream) {
    const float* feat = (const float*)d_in[0];
    const float* Wi   = (const float*)d_in[1];
    const float* bi   = (const float*)d_in[2];
    const float* Wj   = (const float*)d_in[3];
    const float* bj   = (const float*)d_in[4];
    float* out = (float*)d_out;

    float* ws = (float*)d_ws;
    float*  s     = ws + WS_S;
    float*  q     = ws + WS_Q;
    float*  G     = ws + WS_G;
    float*  M     = ws + WS_M;
    __bf16* Pt    = (__bf16*)(ws + WS_PT);
    float*  sPart = ws + WS_SPART;
    __bf16* featT = (__bf16*)(ws + WS_FEATT);

    float* Gpart = out;   // d_out as scratch: 40*65536 floats <= out_size, consumed before k_final

    bool full = (ws_size >= WS_NEED_BYTES);

    k_gram<<<dim3(4, 4, GP_CHUNKS), 256, 0, stream>>>(feat, Gpart);
    if (full) {
        k_trans<<<324, 256, 0, stream>>>(feat, featT, sPart);
        k_reduce<<<65, 256, 0, stream>>>(Gpart, sPart, G, s, 1);
    } else {
        k_rowsum<<<256, 256, 0, stream>>>(feat, s);
        k_reduce<<<64, 256, 0, stream>>>(Gpart, sPart, G, s, 0);
    }
    k_M<<<128, 256, 0, stream>>>(Wj, bj, G, s, M);
    k_P<<<256, 256, 0, stream>>>(Wi, bi, M, Pt, q);
    if (full) {
        k_final<<<dim3(324, 2), 256, 0, stream>>>(feat, featT, Pt, q, out);
    } else {
        k_final_lds<<<324, 256, 0, stream>>>(feat, Pt, q, out);
    }
}

// Round 3
// 123.444 us; speedup vs baseline: 1.2862x; 1.1929x over previous
//
#include <hip/hip_runtime.h>
#include <hip/hip_bf16.h>

#define C 256
#define C2 128
#define NTOK 10368
#define NCHUNK 81            // 81 * 128 = 10368
#define NTILE32 324          // 324 * 32 = 10368

typedef __bf16 bf16x8 __attribute__((ext_vector_type(8)));
typedef float  f32x4  __attribute__((ext_vector_type(4)));

// ws layout (float offsets)
#define WS_Q      0                       // 256
#define WS_PT     256                     // 32768 float-slots = 65536 bf16
#define WS_SPART  33024                   // 324*256 = 82944
#define WS_FEATB  115968                  // 2,654,208 bf16 = 1,327,104 slots
#define WS_FEATT  1443072                 // 1,327,104 slots
#define WS_GPART  2770176                 // 81 * 65536 = 5,308,416
// total 8,078,592 floats = 32.3 MB

__device__ __constant__ int TRI_I[10] = {0,0,0,0,1,1,1,2,2,3};
__device__ __constant__ int TRI_J[10] = {0,1,2,3,1,2,3,2,3,3};

// ---------- k_prep: featB[c][n]=bf16(feat), featT[n][c]=bf16(feat), sPart ----------
// grid 324 (n-tile 32), 256 threads (thread = row c)
__global__ __launch_bounds__(256) void k_prep(const float* __restrict__ feat,
                                              __bf16* __restrict__ featB,
                                              __bf16* __restrict__ featT,
                                              float* __restrict__ sPart) {
    __shared__ __align__(16) ushort Ls[32][C];
    int n0 = blockIdx.x * 32;
    int c = threadIdx.x;

    float vals[32];
    float ssum = 0.f;
#pragma unroll
    for (int i = 0; i < 8; ++i) {
        float4 v = *(const float4*)(feat + (size_t)c * NTOK + n0 + i * 4);
        vals[i * 4 + 0] = v.x; vals[i * 4 + 1] = v.y;
        vals[i * 4 + 2] = v.z; vals[i * 4 + 3] = v.w;
        ssum += v.x + v.y + v.z + v.w;
    }
    sPart[blockIdx.x * C + c] = ssum;

    ushort tmp[32];
#pragma unroll
    for (int n = 0; n < 32; ++n) {
        __bf16 b = (__bf16)vals[n];
        tmp[n] = *(ushort*)&b;
        Ls[n][c] = tmp[n];
    }
    // c-major bf16 (coalesced 16B stores per thread row)
    uint4* bdst = (uint4*)(featB + (size_t)c * NTOK + n0);
#pragma unroll
    for (int i = 0; i < 4; ++i) bdst[i] = ((const uint4*)tmp)[i];

    __syncthreads();
    // n-major bf16 via LDS transpose
    int n = threadIdx.x >> 3;
    int koff = (threadIdx.x & 7) * 32;
    const uint4* src = (const uint4*)&Ls[n][koff];
    uint4* dst = (uint4*)(featT + (size_t)(n0 + n) * C + koff);
#pragma unroll
    for (int i = 0; i < 4; ++i) dst[i] = src[i];
}

// ---------- k_gram: upper-triangle 64x64 tiles of feat@feat^T per 128-col chunk ----------
// grid (10, 81); pure global bf16x8 loads + MFMA, no packing
__global__ __launch_bounds__(256) void k_gram(const __bf16* __restrict__ featB,
                                              float* __restrict__ Gpart) {
    int it = TRI_I[blockIdx.x], jt = TRI_J[blockIdx.x];
    int nc = blockIdx.y;
    int tid = threadIdx.x;
    int wave = tid >> 6, lane = tid & 63;
    int l15 = lane & 15, lq = lane >> 4;

    int i_row = it * 64 + wave * 16 + l15;
    const __bf16* fA = featB + (size_t)i_row * NTOK;
    int nbase = nc * 128;

    f32x4 acc[4];
#pragma unroll
    for (int f = 0; f < 4; ++f) acc[f] = (f32x4){0.f, 0.f, 0.f, 0.f};

#pragma unroll
    for (int ks = 0; ks < 4; ++ks) {
        int n0 = nbase + ks * 32 + lq * 8;
        bf16x8 afrag = *(const bf16x8*)(fA + n0);
#pragma unroll
        for (int f = 0; f < 4; ++f) {
            bf16x8 bfrag = *(const bf16x8*)(featB + (size_t)(jt * 64 + f * 16 + l15) * NTOK + n0);
            acc[f] = __builtin_amdgcn_mfma_f32_16x16x32_bf16(afrag, bfrag, acc[f], 0, 0, 0);
        }
    }

    float* Gp = Gpart + (size_t)nc * (C * C);
    int gib = it * 64 + wave * 16 + lq * 4;
#pragma unroll
    for (int f = 0; f < 4; ++f) {
        int gj = jt * 64 + f * 16 + l15;
#pragma unroll
        for (int r = 0; r < 4; ++r) Gp[(gib + r) * C + gj] = acc[f][r];
        if (it != jt) {
            float4 v = make_float4(acc[f][0], acc[f][1], acc[f][2], acc[f][3]);
            *(float4*)(Gp + (size_t)gj * C + gib) = v;   // mirrored (G symmetric)
        }
    }
}

// ---------- k_mid: per-column fused  G-reduce -> M[:,c] -> Pt[c,:], q[c] ----------
// grid 256 (block = column c), 256 threads
__global__ __launch_bounds__(256) void k_mid(const float* __restrict__ Gpart,
                                             const float* __restrict__ sPart,
                                             const float* __restrict__ Wi,
                                             const float* __restrict__ bi,
                                             const float* __restrict__ Wj,
                                             const float* __restrict__ bj,
                                             __bf16* __restrict__ Pt,
                                             float* __restrict__ q) {
    __shared__ float Gcol[C];
    __shared__ float Mpart[C];
    __shared__ float Mcol[C2];
    __shared__ float sred[8];
    int c = blockIdx.x, t = threadIdx.x;

    // G column c == row c (symmetry): coalesced reduction over 81 chunk partials
    float g = 0.f;
    const float* gp = Gpart + (size_t)c * C + t;
#pragma unroll 3
    for (int p = 0; p < NCHUNK; ++p) g += gp[(size_t)p * (C * C)];
    Gcol[t] = g;

    // s[c] = total row sum
    float sv = 0.f;
    for (int p = t; p < NTILE32; p += 256) sv += sPart[p * C + c];
    for (int off = 32; off > 0; off >>= 1) sv += __shfl_xor(sv, off);
    if ((t & 63) == 0) sred[t >> 6] = sv;
    __syncthreads();
    float s_c = sred[0] + sred[1] + sred[2] + sred[3];

    // M[m,c] = Wj[m,:].Gcol + bj[m]*s_c   (split k-range across thread halves)
    int m = t & 127, h = t >> 7;
    float a = 0.f;
#pragma unroll 8
    for (int k0 = h * 128; k0 < h * 128 + 128; k0 += 4) {
        float4 w = *(const float4*)(Wj + m * C + k0);
        a += w.x * Gcol[k0] + w.y * Gcol[k0 + 1] + w.z * Gcol[k0 + 2] + w.w * Gcol[k0 + 3];
    }
    Mpart[t] = a;
    __syncthreads();
    if (t < C2) Mcol[t] = Mpart[t] + Mpart[t + 128] + bj[t] * s_c;
    __syncthreads();

    // Pt[c,k] = (Wi[:,k].Mcol)/N  (coalesced Wi reads), q[c] = (bi.Mcol)/N
    float acc = 0.f;
#pragma unroll 8
    for (int mm = 0; mm < C2; ++mm) acc += Wi[mm * C + t] * Mcol[mm];
    Pt[(size_t)c * C + t] = (__bf16)(acc * (1.0f / NTOK));

    float qv = (t < C2) ? bi[t] * Mcol[t] : 0.f;
    for (int off = 32; off > 0; off >>= 1) qv += __shfl_xor(qv, off);
    if ((t & 63) == 0) sred[4 + (t >> 6)] = qv;
    __syncthreads();
    if (t == 0) q[c] = (sred[4] + sred[5] + sred[6] + sred[7]) * (1.0f / NTOK);
}

// ---------- k_final: out[c,n] = feat[c,n] + q[c] + sum_k Pt[c,k] featT[n,k] ----------
// grid (324, 2); no LDS, no barriers
__global__ __launch_bounds__(256) void k_final(const float* __restrict__ feat,
                                               const __bf16* __restrict__ featT,
                                               const __bf16* __restrict__ Pt,
                                               const float* __restrict__ q,
                                               float* __restrict__ out) {
    int n0 = blockIdx.x * 32;
    int cbase = blockIdx.y * 128;
    int tid = threadIdx.x;
    int wave = tid >> 6, lane = tid & 63;
    int l15 = lane & 15, lq = lane >> 4;

    f32x4 acc[2][2];
#pragma unroll
    for (int si = 0; si < 2; ++si)
#pragma unroll
        for (int ns = 0; ns < 2; ++ns) acc[si][ns] = (f32x4){0.f, 0.f, 0.f, 0.f};

#pragma unroll
    for (int ks = 0; ks < 8; ++ks) {
        int k0 = ks * 32;
        bf16x8 b[2];
#pragma unroll
        for (int ns = 0; ns < 2; ++ns)
            b[ns] = *(const bf16x8*)(featT + (size_t)(n0 + ns * 16 + l15) * C + k0 + lq * 8);
#pragma unroll
        for (int si = 0; si < 2; ++si) {
            int crow = cbase + wave * 32 + si * 16 + l15;
            bf16x8 a = *(const bf16x8*)(Pt + (size_t)crow * C + k0 + lq * 8);
#pragma unroll
            for (int ns = 0; ns < 2; ++ns)
                acc[si][ns] = __builtin_amdgcn_mfma_f32_16x16x32_bf16(a, b[ns], acc[si][ns], 0, 0, 0);
        }
    }

#pragma unroll
    for (int si = 0; si < 2; ++si)
#pragma unroll
        for (int ns = 0; ns < 2; ++ns)
#pragma unroll
            for (int r = 0; r < 4; ++r) {
                int c = cbase + wave * 32 + si * 16 + lq * 4 + r;
                int n = n0 + ns * 16 + l15;
                out[(size_t)c * NTOK + n] = feat[(size_t)c * NTOK + n] + q[c] + acc[si][ns][r];
            }
}

extern "C" void kernel_launch(void* const* d_in, const int* in_sizes, int n_in,
                              void* d_out, int out_size, void* d_ws, size_t ws_size,
                              hipStream_t stream) {
    const float* feat = (const float*)d_in[0];
    const float* Wi   = (const float*)d_in[1];
    const float* bi   = (const float*)d_in[2];
    const float* Wj   = (const float*)d_in[3];
    const float* bj   = (const float*)d_in[4];
    float* out = (float*)d_out;

    float* ws = (float*)d_ws;
    float*  q     = ws + WS_Q;
    __bf16* Pt    = (__bf16*)(ws + WS_PT);
    float*  sPart = ws + WS_SPART;
    __bf16* featB = (__bf16*)(ws + WS_FEATB);
    __bf16* featT = (__bf16*)(ws + WS_FEATT);
    float*  Gpart = ws + WS_GPART;

    k_prep <<<NTILE32, 256, 0, stream>>>(feat, featB, featT, sPart);
    k_gram <<<dim3(10, NCHUNK), 256, 0, stream>>>(featB, Gpart);
    k_mid  <<<256, 256, 0, stream>>>(Gpart, sPart, Wi, bi, Wj, bj, Pt, q);
    k_final<<<dim3(NTILE32, 2), 256, 0, stream>>>(feat, featT, Pt, q, out);
}

// Round 4
// 119.851 us; speedup vs baseline: 1.3247x; 1.0300x over previous
//
#include <hip/hip_runtime.h>
#include <hip/hip_bf16.h>

#define C 256
#define C2 128
#define NTOK 10368
#define NCHUNK 36            // 36 * 288 = 10368
#define KSTEPS 9             // 288 / 32
#define NTILE32 324          // 324 * 32 = 10368

typedef __bf16 bf16x8 __attribute__((ext_vector_type(8)));
typedef float  f32x4  __attribute__((ext_vector_type(4)));

// ws layout (float offsets)
#define WS_Q      0                       // 256
#define WS_PT     256                     // 32768 float-slots = 65536 bf16
#define WS_SPART  33024                   // 324*256 = 82944
#define WS_FEATB  115968                  // 2,654,208 bf16 = 1,327,104 slots
#define WS_FEATT  1443072                 // 1,327,104 slots
#define WS_GPART  2770176                 // 36 * 65536 = 2,359,296
// total ~5.13M floats = 20.5 MB

__device__ __constant__ int TRI_I[10] = {0,0,0,0,1,1,1,2,2,3};
__device__ __constant__ int TRI_J[10] = {0,1,2,3,1,2,3,2,3,3};

// ---------- k_prep: featB[c][n]=bf16(feat), featT[n][c]=bf16(feat), sPart ----------
// grid 324 (n-tile 32), 256 threads (thread = row c)
__global__ __launch_bounds__(256) void k_prep(const float* __restrict__ feat,
                                              __bf16* __restrict__ featB,
                                              __bf16* __restrict__ featT,
                                              float* __restrict__ sPart) {
    __shared__ __align__(16) ushort Ls[32][C];
    int n0 = blockIdx.x * 32;
    int c = threadIdx.x;

    float vals[32];
    float ssum = 0.f;
#pragma unroll
    for (int i = 0; i < 8; ++i) {
        float4 v = *(const float4*)(feat + (size_t)c * NTOK + n0 + i * 4);
        vals[i * 4 + 0] = v.x; vals[i * 4 + 1] = v.y;
        vals[i * 4 + 2] = v.z; vals[i * 4 + 3] = v.w;
        ssum += v.x + v.y + v.z + v.w;
    }
    sPart[blockIdx.x * C + c] = ssum;

    ushort tmp[32];
#pragma unroll
    for (int n = 0; n < 32; ++n) {
        __bf16 b = (__bf16)vals[n];
        tmp[n] = *(ushort*)&b;
        Ls[n][c] = tmp[n];
    }
    // c-major bf16 (coalesced 16B stores per thread row)
    uint4* bdst = (uint4*)(featB + (size_t)c * NTOK + n0);
#pragma unroll
    for (int i = 0; i < 4; ++i) bdst[i] = ((const uint4*)tmp)[i];

    __syncthreads();
    // n-major bf16 via LDS transpose
    int n = threadIdx.x >> 3;
    int koff = (threadIdx.x & 7) * 32;
    const uint4* src = (const uint4*)&Ls[n][koff];
    uint4* dst = (uint4*)(featT + (size_t)(n0 + n) * C + koff);
#pragma unroll
    for (int i = 0; i < 4; ++i) dst[i] = src[i];
}

// ---------- k_gram: upper-triangle 64x64 tiles of feat@feat^T per 288-col chunk ----------
// grid (10, 36); pure global bf16x8 loads + MFMA, no packing
__global__ __launch_bounds__(256) void k_gram(const __bf16* __restrict__ featB,
                                              float* __restrict__ Gpart) {
    int it = TRI_I[blockIdx.x], jt = TRI_J[blockIdx.x];
    int nc = blockIdx.y;
    int tid = threadIdx.x;
    int wave = tid >> 6, lane = tid & 63;
    int l15 = lane & 15, lq = lane >> 4;

    int i_row = it * 64 + wave * 16 + l15;
    const __bf16* fA = featB + (size_t)i_row * NTOK;
    int nbase = nc * (KSTEPS * 32);

    f32x4 acc[4];
#pragma unroll
    for (int f = 0; f < 4; ++f) acc[f] = (f32x4){0.f, 0.f, 0.f, 0.f};

#pragma unroll
    for (int ks = 0; ks < KSTEPS; ++ks) {
        int n0 = nbase + ks * 32 + lq * 8;
        bf16x8 afrag = *(const bf16x8*)(fA + n0);
#pragma unroll
        for (int f = 0; f < 4; ++f) {
            bf16x8 bfrag = *(const bf16x8*)(featB + (size_t)(jt * 64 + f * 16 + l15) * NTOK + n0);
            acc[f] = __builtin_amdgcn_mfma_f32_16x16x32_bf16(afrag, bfrag, acc[f], 0, 0, 0);
        }
    }

    float* Gp = Gpart + (size_t)nc * (C * C);
    int gib = it * 64 + wave * 16 + lq * 4;
#pragma unroll
    for (int f = 0; f < 4; ++f) {
        int gj = jt * 64 + f * 16 + l15;
#pragma unroll
        for (int r = 0; r < 4; ++r) Gp[(gib + r) * C + gj] = acc[f][r];
        if (it != jt) {
            float4 v = make_float4(acc[f][0], acc[f][1], acc[f][2], acc[f][3]);
            *(float4*)(Gp + (size_t)gj * C + gib) = v;   // mirrored (G symmetric)
        }
    }
}

// ---------- k_mid: per-column fused  G-reduce -> M[:,c] -> Pt[c,:], q[c] ----------
// grid 256 (block = column c), 256 threads
__global__ __launch_bounds__(256) void k_mid(const float* __restrict__ Gpart,
                                             const float* __restrict__ sPart,
                                             const float* __restrict__ Wi,
                                             const float* __restrict__ bi,
                                             const float* __restrict__ Wj,
                                             const float* __restrict__ bj,
                                             __bf16* __restrict__ Pt,
                                             float* __restrict__ q) {
    __shared__ float Gcol[C];
    __shared__ float Mpart[C];
    __shared__ float Mcol[C2];
    __shared__ float sred[8];
    int c = blockIdx.x, t = threadIdx.x;

    // G column c == row c (symmetry): coalesced reduction over chunk partials
    float g = 0.f;
    const float* gp = Gpart + (size_t)c * C + t;
#pragma unroll 4
    for (int p = 0; p < NCHUNK; ++p) g += gp[(size_t)p * (C * C)];
    Gcol[t] = g;

    // s[c] = total row sum
    float sv = 0.f;
    for (int p = t; p < NTILE32; p += 256) sv += sPart[p * C + c];
    for (int off = 32; off > 0; off >>= 1) sv += __shfl_xor(sv, off);
    if ((t & 63) == 0) sred[t >> 6] = sv;
    __syncthreads();
    float s_c = sred[0] + sred[1] + sred[2] + sred[3];

    // M[m,c] = Wj[m,:].Gcol + bj[m]*s_c   (split k-range across thread halves)
    int m = t & 127, h = t >> 7;
    float a = 0.f;
#pragma unroll 8
    for (int k0 = h * 128; k0 < h * 128 + 128; k0 += 4) {
        float4 w = *(const float4*)(Wj + m * C + k0);
        a += w.x * Gcol[k0] + w.y * Gcol[k0 + 1] + w.z * Gcol[k0 + 2] + w.w * Gcol[k0 + 3];
    }
    Mpart[t] = a;
    __syncthreads();
    if (t < C2) Mcol[t] = Mpart[t] + Mpart[t + 128] + bj[t] * s_c;
    __syncthreads();

    // Pt[c,k] = (Wi[:,k].Mcol)/N  (coalesced Wi reads), q[c] = (bi.Mcol)/N
    float acc = 0.f;
#pragma unroll 8
    for (int mm = 0; mm < C2; ++mm) acc += Wi[mm * C + t] * Mcol[mm];
    Pt[(size_t)c * C + t] = (__bf16)(acc * (1.0f / NTOK));

    float qv = (t < C2) ? bi[t] * Mcol[t] : 0.f;
    for (int off = 32; off > 0; off >>= 1) qv += __shfl_xor(qv, off);
    if ((t & 63) == 0) sred[4 + (t >> 6)] = qv;
    __syncthreads();
    if (t == 0) q[c] = (sred[4] + sred[5] + sred[6] + sred[7]) * (1.0f / NTOK);
}

// ---------- k_final: out[c,n] = featB[c,n] + q[c] + sum_k Pt[c,k] featT[n,k] ----------
// grid (324, 2); no LDS, no barriers; residual from bf16 featB (halves residual fetch)
__global__ __launch_bounds__(256) void k_final(const __bf16* __restrict__ featB,
                                               const __bf16* __restrict__ featT,
                                               const __bf16* __restrict__ Pt,
                                               const float* __restrict__ q,
                                               float* __restrict__ out) {
    int n0 = blockIdx.x * 32;
    int cbase = blockIdx.y * 128;
    int tid = threadIdx.x;
    int wave = tid >> 6, lane = tid & 63;
    int l15 = lane & 15, lq = lane >> 4;

    f32x4 acc[2][2];
#pragma unroll
    for (int si = 0; si < 2; ++si)
#pragma unroll
        for (int ns = 0; ns < 2; ++ns) acc[si][ns] = (f32x4){0.f, 0.f, 0.f, 0.f};

#pragma unroll
    for (int ks = 0; ks < 8; ++ks) {
        int k0 = ks * 32;
        bf16x8 b[2];
#pragma unroll
        for (int ns = 0; ns < 2; ++ns)
            b[ns] = *(const bf16x8*)(featT + (size_t)(n0 + ns * 16 + l15) * C + k0 + lq * 8);
#pragma unroll
        for (int si = 0; si < 2; ++si) {
            int crow = cbase + wave * 32 + si * 16 + l15;
            bf16x8 a = *(const bf16x8*)(Pt + (size_t)crow * C + k0 + lq * 8);
#pragma unroll
            for (int ns = 0; ns < 2; ++ns)
                acc[si][ns] = __builtin_amdgcn_mfma_f32_16x16x32_bf16(a, b[ns], acc[si][ns], 0, 0, 0);
        }
    }

#pragma unroll
    for (int si = 0; si < 2; ++si)
#pragma unroll
        for (int ns = 0; ns < 2; ++ns)
#pragma unroll
            for (int r = 0; r < 4; ++r) {
                int c = cbase + wave * 32 + si * 16 + lq * 4 + r;
                int n = n0 + ns * 16 + l15;
                float res = (float)featB[(size_t)c * NTOK + n];
                out[(size_t)c * NTOK + n] = res + q[c] + acc[si][ns][r];
            }
}

extern "C" void kernel_launch(void* const* d_in, const int* in_sizes, int n_in,
                              void* d_out, int out_size, void* d_ws, size_t ws_size,
                              hipStream_t stream) {
    const float* feat = (const float*)d_in[0];
    const float* Wi   = (const float*)d_in[1];
    const float* bi   = (const float*)d_in[2];
    const float* Wj   = (const float*)d_in[3];
    const float* bj   = (const float*)d_in[4];
    float* out = (float*)d_out;

    float* ws = (float*)d_ws;
    float*  q     = ws + WS_Q;
    __bf16* Pt    = (__bf16*)(ws + WS_PT);
    float*  sPart = ws + WS_SPART;
    __bf16* featB = (__bf16*)(ws + WS_FEATB);
    __bf16* featT = (__bf16*)(ws + WS_FEATT);
    float*  Gpart = ws + WS_GPART;

    k_prep <<<NTILE32, 256, 0, stream>>>(feat, featB, featT, sPart);
    k_gram <<<dim3(10, NCHUNK), 256, 0, stream>>>(featB, Gpart);
    k_mid  <<<256, 256, 0, stream>>>(Gpart, sPart, Wi, bi, Wj, bj, Pt, q);
    k_final<<<dim3(NTILE32, 2), 256, 0, stream>>>(featB, featT, Pt, q, out);
}